// Round 3
// baseline (308.031 us; speedup 1.0000x reference)
//
#include <hip/hip_runtime.h>
#include <math.h>

// HiPPO-LegS kernel: K[d, l] = C[d]^T A_bar^l B_bar[d], D=1024, N=64, L=4096.
// l = 64q + r decomposition; G_r = A_bar^r, H_q = (A_bar^64)^q via squarings
// S_j = A_bar^(2^j), j=0..11.
// Round 3: software-pipelined register-tiled matmuls everywhere (prefetch the
// next 4k-chunk while FMAing the current), more waves/CU for k_expand (8) and
// k_contract (8). Latency exposure was the round-2 killer (VALUBusy 0.065%).

#define PAD 68

// ws layout (float offsets). Total 9,031,744 floats = 36.1 MB.
#define WS_DT     0
#define WS_S      64                       // 12 matrices of 4096
#define WS_MINVT  (WS_S + 12*4096)         // 49216
#define WS_BBAR   (WS_MINVT + 4096)        // 53312, 1024x64
#define WS_G      (WS_BBAR + 1024*64)      // 118848, 64 x 4096 (G_r row-major [k][n])
#define WS_HT     (WS_G + 64*4096)         // 380992, 64 x 4096 (H_q^T: [k][n] = H[n][k])
#define WS_W      (WS_HT + 64*4096)        // 643136, [d][r][n]
#define WS_X      (WS_W + 1024*4096)       // 4837440, [d][q][n]

__device__ __forceinline__ float f4c(const float4 v, int kk) {
  return kk == 0 ? v.x : kk == 1 ? v.y : kk == 2 ? v.z : v.w;
}

// 64x64x64 matmul c = a @ b (all LDS pad-68). 128 threads, 8x4 tiles,
// software-pipelined: prefetch chunk kc+1 while FMAing chunk kc.
__device__ __forceinline__ void mm64_128p(const float* __restrict__ a,
                                          const float* __restrict__ b,
                                          float* __restrict__ c, int tid) {
  const int tx = tid & 15, ty = tid >> 4;
  const int n0 = tx * 4;
  float4 acc[8];
#pragma unroll
  for (int ii = 0; ii < 8; ++ii) acc[ii] = make_float4(0.f, 0.f, 0.f, 0.f);
  float4 av[2][8], bv[2][4];
#pragma unroll
  for (int ii = 0; ii < 8; ++ii) av[0][ii] = *(const float4*)&a[(ty + 8 * ii) * PAD];
#pragma unroll
  for (int kk = 0; kk < 4; ++kk) bv[0][kk] = *(const float4*)&b[kk * PAD + n0];
#pragma unroll
  for (int kc = 0; kc < 16; ++kc) {
    const int cur = kc & 1, nxt = cur ^ 1;
    if (kc < 15) {
      const int k2 = (kc + 1) * 4;
#pragma unroll
      for (int ii = 0; ii < 8; ++ii)
        av[nxt][ii] = *(const float4*)&a[(ty + 8 * ii) * PAD + k2];
#pragma unroll
      for (int kk = 0; kk < 4; ++kk)
        bv[nxt][kk] = *(const float4*)&b[(kc * 4 + 4 + kk) * PAD + n0];
    }
#pragma unroll
    for (int kk = 0; kk < 4; ++kk) {
      const float4 bb = bv[cur][kk];
#pragma unroll
      for (int ii = 0; ii < 8; ++ii) {
        const float s = f4c(av[cur][ii], kk);
        acc[ii].x += s * bb.x; acc[ii].y += s * bb.y;
        acc[ii].z += s * bb.z; acc[ii].w += s * bb.w;
      }
    }
  }
#pragma unroll
  for (int ii = 0; ii < 8; ++ii)
    *(float4*)&c[(ty + 8 * ii) * PAD + n0] = acc[ii];
}

// global row-major 64x64 -> LDS pad-68
template <int NT>
__device__ __forceinline__ void stage(const float* __restrict__ g,
                                      float* __restrict__ l, int tid) {
  for (int e = tid; e < 1024; e += NT) {
    const int row = e >> 4, c4 = (e & 15) << 2;
    *(float4*)&l[row * PAD + c4] = *(const float4*)&g[row * 64 + c4];
  }
}

// LDS pad-68 -> global row-major 64x64 (scaled)
template <int NT>
__device__ __forceinline__ void unstage(const float* __restrict__ l,
                                        float* __restrict__ g, int tid,
                                        float scale) {
  for (int e = tid; e < 1024; e += NT) {
    const int row = e >> 4, c4 = (e & 15) << 2;
    float4 v = *(const float4*)&l[row * PAD + c4];
    v.x *= scale; v.y *= scale; v.z *= scale; v.w *= scale;
    *(float4*)&g[row * 64 + c4] = v;
  }
}

// ---------------------------------------------------------------------------
// K1: one block, 128 threads.
// dt; recursive-doubling inverse of lower-triangular M = I - (dt/2)A
// (diag >= 1.05, no pivoting); A_bar = 2*Minv - I; 11 pipelined squarings.
// ---------------------------------------------------------------------------
__global__ __launch_bounds__(128) void k_setup(const float* __restrict__ A,
                                               const float* __restrict__ logdt,
                                               float* __restrict__ ws) {
  __shared__ float Msh[64 * 65];
  __shared__ float Tm[64 * 65];
  __shared__ float tmpb[1024];
  __shared__ __align__(16) float bufA[64 * PAD];
  __shared__ __align__(16) float bufB[64 * PAD];
  const int tid = threadIdx.x;
  const float dt = expf(logdt[0]);
  const float hdt = 0.5f * dt;
  if (tid == 0) ws[WS_DT] = dt;

  for (int idx = tid; idx < 4096; idx += 128) {
    const int i = idx >> 6, j = idx & 63;
    Msh[i * 65 + j] = ((i == j) ? 1.f : 0.f) - hdt * A[idx];
    Tm[i * 65 + j] = 0.f;
  }
  __syncthreads();
  if (tid < 64) Tm[tid * 65 + tid] = 1.0f / Msh[tid * 65 + tid];
  __syncthreads();

  // Recursive doubling: T21 = -T22 * M21 * T11 per diagonal block pair.
  for (int lb = 0; lb < 6; ++lb) {
    const int b = 1 << lb;
    const int E = 32 * b;
    for (int e = tid; e < E; e += 128) {
      const int rem = e & (b * b - 1);
      const int p = e >> (2 * lb);
      const int i = rem >> lb, j = rem & (b - 1);
      const int c0 = p << (lb + 1), r0 = c0 + b;
      float s = 0.f;
      for (int k = 0; k < b; ++k)
        s += Msh[(r0 + i) * 65 + c0 + k] * Tm[(c0 + k) * 65 + c0 + j];
      tmpb[e] = s;
    }
    __syncthreads();
    for (int e = tid; e < E; e += 128) {
      const int rem = e & (b * b - 1);
      const int p = e >> (2 * lb);
      const int i = rem >> lb, j = rem & (b - 1);
      const int c0 = p << (lb + 1), r0 = c0 + b;
      float s = 0.f;
      const float* tp = &tmpb[e - rem];
      for (int k = 0; k < b; ++k)
        s += Tm[(r0 + i) * 65 + r0 + k] * tp[k * b + j];
      Tm[(r0 + i) * 65 + c0 + j] = -s;
    }
    __syncthreads();
  }

  // Minv^T to ws (for B_bar).
  for (int idx = tid; idx < 4096; idx += 128) {
    const int k = idx >> 6, n = idx & 63;
    ws[WS_MINVT + idx] = Tm[n * 65 + k];
  }
  // A_bar = 2*Minv - I -> bufA (padded) and ws S_0.
  for (int idx = tid; idx < 4096; idx += 128) {
    const int i = idx >> 6, j = idx & 63;
    const float v = 2.f * Tm[i * 65 + j] - ((i == j) ? 1.f : 0.f);
    bufA[i * PAD + j] = v;
    ws[WS_S + idx] = v;
  }
  __syncthreads();

  float* cur = bufA;
  float* nxt = bufB;
  for (int sj = 1; sj < 12; ++sj) {
    mm64_128p(cur, cur, nxt, tid);
    __syncthreads();
    unstage<128>(nxt, ws + WS_S + sj * 4096, tid, 1.f);
    float* t = cur; cur = nxt; nxt = t;
  }
}

// ---------------------------------------------------------------------------
// K2: 144 blocks x 128.
//   p in [0,64):    G_r  = prod S_j over set bits of r   (row-major)
//   p in [64,128):  H_q^T (transposed store)
//   p in [128,144): B_bar chunk: dt * B_chunk @ Minv^T
// ---------------------------------------------------------------------------
__global__ __launch_bounds__(128) void k_powers(const float* __restrict__ Bg,
                                                float* __restrict__ ws) {
  __shared__ __align__(16) float ra[64 * PAD];
  __shared__ __align__(16) float rb[64 * PAD];
  __shared__ __align__(16) float sm[64 * PAD];
  const int p = blockIdx.x, tid = threadIdx.x;

  if (p < 128) {
    const int chain = p >> 6, r = p & 63;
    float* cur = ra;
    float* nxt = rb;
    if (r == 0) {
      for (int idx = tid; idx < 4096; idx += 128) {
        const int i = idx >> 6, j = idx & 63;
        cur[i * PAD + j] = (i == j) ? 1.f : 0.f;
      }
    } else {
      const int j0 = __ffs(r) - 1;
      stage<128>(ws + WS_S + (chain * 6 + j0) * 4096, cur, tid);
      for (int j = j0 + 1; j < 6; ++j) {
        if ((r >> j) & 1) {  // block-uniform branch
          __syncthreads();
          stage<128>(ws + WS_S + (chain * 6 + j) * 4096, sm, tid);
          __syncthreads();
          mm64_128p(cur, sm, nxt, tid);
          __syncthreads();
          float* t = cur; cur = nxt; nxt = t;
        }
      }
    }
    __syncthreads();
    if (chain == 0) {
      unstage<128>(cur, ws + WS_G + r * 4096, tid, 1.f);
    } else {
      float* HT = ws + WS_HT + r * 4096;
      for (int idx = tid; idx < 4096; idx += 128) {
        const int k = idx >> 6, n = idx & 63;
        HT[idx] = cur[n * PAD + k];
      }
    }
  } else {
    const int d0 = (p - 128) * 64;
    stage<128>(ws + WS_MINVT, sm, tid);
    stage<128>(Bg + d0 * 64, ra, tid);
    __syncthreads();
    mm64_128p(ra, sm, rb, tid);
    __syncthreads();
    unstage<128>(rb, ws + WS_BBAR + d0 * 64, tid, ws[WS_DT]);
  }
}

// ---------------------------------------------------------------------------
// K3: 2048 blocks x 128. Block = (chain, rr, dch); both waves same rr,
// columns split by wave (n in [32w, 32w+32)). 8x4 tiles, pipelined.
// chain0: W[d0.., rr, :] = C_chunk @ G_rr; chain1: X = Bbar_chunk @ H_rr^T.
// LDS 34.8 KB -> 4 blocks/CU = 8 waves/CU.
// ---------------------------------------------------------------------------
__global__ __launch_bounds__(128) void k_expand(const float* __restrict__ Cg,
                                                float* __restrict__ ws) {
  __shared__ __align__(16) float matL[64 * PAD];
  __shared__ __align__(16) float srcL[64 * PAD];
  const int p = blockIdx.x, tid = threadIdx.x;
  const int chain = p >> 10, rr = (p >> 4) & 63, dch = p & 15;
  const int w = tid >> 6, lt = tid & 63;
  const int d0 = dch * 64;
  const float* msrc = ws + (chain ? WS_HT : WS_G) + rr * 4096;
  const float* vsrc = chain ? (ws + WS_BBAR + d0 * 64) : (Cg + d0 * 64);

  stage<128>(msrc, matL, tid);
  stage<128>(vsrc, srcL, tid);
  __syncthreads();

  const int tx = lt & 7, ty = lt >> 3;
  const int n0 = 32 * w + 4 * tx;
  float4 acc[8];
#pragma unroll
  for (int ii = 0; ii < 8; ++ii) acc[ii] = make_float4(0.f, 0.f, 0.f, 0.f);
  float4 av[2][8], bv[2][4];
#pragma unroll
  for (int ii = 0; ii < 8; ++ii) av[0][ii] = *(const float4*)&srcL[(ty + 8 * ii) * PAD];
#pragma unroll
  for (int kk = 0; kk < 4; ++kk) bv[0][kk] = *(const float4*)&matL[kk * PAD + n0];
#pragma unroll
  for (int kc = 0; kc < 16; ++kc) {
    const int cur = kc & 1, nxt = cur ^ 1;
    if (kc < 15) {
      const int k2 = (kc + 1) * 4;
#pragma unroll
      for (int ii = 0; ii < 8; ++ii)
        av[nxt][ii] = *(const float4*)&srcL[(ty + 8 * ii) * PAD + k2];
#pragma unroll
      for (int kk = 0; kk < 4; ++kk)
        bv[nxt][kk] = *(const float4*)&matL[(k2 + kk) * PAD + n0];
    }
#pragma unroll
    for (int kk = 0; kk < 4; ++kk) {
      const float4 bb = bv[cur][kk];
#pragma unroll
      for (int ii = 0; ii < 8; ++ii) {
        const float s = f4c(av[cur][ii], kk);
        acc[ii].x += s * bb.x; acc[ii].y += s * bb.y;
        acc[ii].z += s * bb.z; acc[ii].w += s * bb.w;
      }
    }
  }
  float* dst = ws + (chain ? WS_X : WS_W);
#pragma unroll
  for (int ii = 0; ii < 8; ++ii)
    *(float4*)&dst[(d0 + ty + 8 * ii) * 4096 + rr * 64 + n0] = acc[ii];
}

// ---------------------------------------------------------------------------
// K4: 1024 blocks x 128, one block per d, 2 waves.
// K[q*64+r] = sum_n W[r,n] X[q,n]; r = (lt&15)+16*ri, q = (lt>>4)+4*w+8*qj.
// 4x8 tiles, pipelined. + D[d] at l==0. LDS 34.8KB -> 4 blocks/CU, 8 waves/CU.
// ---------------------------------------------------------------------------
__global__ __launch_bounds__(128) void k_contract(const float* __restrict__ Dg,
                                                  const float* __restrict__ ws,
                                                  float* __restrict__ out) {
  __shared__ __align__(16) float Wl[64 * PAD];
  __shared__ __align__(16) float Xl[64 * PAD];
  const int d = blockIdx.x, tid = threadIdx.x;
  stage<128>(ws + WS_W + d * 4096, Wl, tid);
  stage<128>(ws + WS_X + d * 4096, Xl, tid);
  __syncthreads();

  const int w = tid >> 6, lt = tid & 63;
  const int rt = lt & 15, qt = (lt >> 4) + 4 * w;
  float acc[4][8];
#pragma unroll
  for (int ii = 0; ii < 4; ++ii)
#pragma unroll
    for (int jj = 0; jj < 8; ++jj) acc[ii][jj] = 0.f;

  float4 Wv[2][4], Xv[2][8];
#pragma unroll
  for (int ii = 0; ii < 4; ++ii) Wv[0][ii] = *(const float4*)&Wl[(rt + 16 * ii) * PAD];
#pragma unroll
  for (int jj = 0; jj < 8; ++jj) Xv[0][jj] = *(const float4*)&Xl[(qt + 8 * jj) * PAD];
#pragma unroll
  for (int nc = 0; nc < 16; ++nc) {
    const int cur = nc & 1, nxt = cur ^ 1;
    if (nc < 15) {
      const int n2 = (nc + 1) * 4;
#pragma unroll
      for (int ii = 0; ii < 4; ++ii)
        Wv[nxt][ii] = *(const float4*)&Wl[(rt + 16 * ii) * PAD + n2];
#pragma unroll
      for (int jj = 0; jj < 8; ++jj)
        Xv[nxt][jj] = *(const float4*)&Xl[(qt + 8 * jj) * PAD + n2];
    }
#pragma unroll
    for (int jj = 0; jj < 8; ++jj) {
      const float4 xv = Xv[cur][jj];
#pragma unroll
      for (int ii = 0; ii < 4; ++ii) {
        const float4 wv = Wv[cur][ii];
        acc[ii][jj] += wv.x * xv.x + wv.y * xv.y + wv.z * xv.z + wv.w * xv.w;
      }
    }
  }
  const float dval = Dg[d];
  float* od = out + d * 4096;
#pragma unroll
  for (int jj = 0; jj < 8; ++jj) {
#pragma unroll
    for (int ii = 0; ii < 4; ++ii) {
      const int q = qt + 8 * jj, r = rt + 16 * ii;
      const int l = q * 64 + r;
      od[l] = acc[ii][jj] + ((l == 0) ? dval : 0.f);
    }
  }
}

extern "C" void kernel_launch(void* const* d_in, const int* in_sizes, int n_in,
                              void* d_out, int out_size, void* d_ws, size_t ws_size,
                              hipStream_t stream) {
  const float* A     = (const float*)d_in[0];  // A_ct 64x64
  const float* B     = (const float*)d_in[1];  // 1024x64
  const float* C     = (const float*)d_in[2];  // 1024x64
  const float* Dv    = (const float*)d_in[3];  // 1024
  const float* logdt = (const float*)d_in[4];  // scalar
  float* ws  = (float*)d_ws;                   // 36.2 MB
  float* out = (float*)d_out;                  // 1024*4096 fp32

  hipLaunchKernelGGL(k_setup,    dim3(1),    dim3(128), 0, stream, A, logdt, ws);
  hipLaunchKernelGGL(k_powers,   dim3(144),  dim3(128), 0, stream, B, ws);
  hipLaunchKernelGGL(k_expand,   dim3(2048), dim3(128), 0, stream, C, ws);
  hipLaunchKernelGGL(k_contract, dim3(1024), dim3(128), 0, stream, Dv, ws, out);
}

// Round 4
// 204.783 us; speedup vs baseline: 1.5042x; 1.5042x over previous
//
#include <hip/hip_runtime.h>
#include <math.h>

// HiPPO-LegS kernel: K[d, l] = C[d]^T A_bar^l B_bar[d], D=1024, N=64, L=4096.
// l = 64q + r decomposition; G_r = A_bar^r, H_q = (A_bar^64)^q via squarings
// S_j = A_bar^(2^j), j=0..11.
// Round 4: R3's manual double-buffer in expand/contract blew VGPR to 256 ->
// scratch spills (118MB WRITE_SIZE). Revert those to simple 256-thread
// register-tiled loops (VGPR ~70, 4 blocks/CU, 16 waves/CU does the hiding).
// Keep pipelined mm only in the occupancy-starved setup/powers kernels.

#define PAD 68

// ws layout (float offsets). Total 9,031,744 floats = 36.1 MB.
#define WS_DT     0
#define WS_S      64                       // 12 matrices of 4096
#define WS_MINVT  (WS_S + 12*4096)         // 49216
#define WS_BBAR   (WS_MINVT + 4096)        // 53312, 1024x64
#define WS_G      (WS_BBAR + 1024*64)      // 118848, 64 x 4096 (G_r row-major [k][n])
#define WS_HT     (WS_G + 64*4096)         // 380992, 64 x 4096 (H_q^T: [k][n] = H[n][k])
#define WS_W      (WS_HT + 64*4096)        // 643136, [d][r][n]
#define WS_X      (WS_W + 1024*4096)       // 4837440, [d][q][n]

__device__ __forceinline__ float f4c(const float4 v, int kk) {
  return kk == 0 ? v.x : kk == 1 ? v.y : kk == 2 ? v.z : v.w;
}

// 64x64x64 matmul c = a @ b (all LDS pad-68). 128 threads, 8x4 tiles,
// software-pipelined (only used in 1-2 block kernels where occupancy can't
// hide LDS latency). VGPR ~170 at 128 threads: no spill.
__device__ __forceinline__ void mm64_128p(const float* __restrict__ a,
                                          const float* __restrict__ b,
                                          float* __restrict__ c, int tid) {
  const int tx = tid & 15, ty = tid >> 4;
  const int n0 = tx * 4;
  float4 acc[8];
#pragma unroll
  for (int ii = 0; ii < 8; ++ii) acc[ii] = make_float4(0.f, 0.f, 0.f, 0.f);
  float4 av[2][8], bv[2][4];
#pragma unroll
  for (int ii = 0; ii < 8; ++ii) av[0][ii] = *(const float4*)&a[(ty + 8 * ii) * PAD];
#pragma unroll
  for (int kk = 0; kk < 4; ++kk) bv[0][kk] = *(const float4*)&b[kk * PAD + n0];
#pragma unroll
  for (int kc = 0; kc < 16; ++kc) {
    const int cur = kc & 1, nxt = cur ^ 1;
    if (kc < 15) {
      const int k2 = (kc + 1) * 4;
#pragma unroll
      for (int ii = 0; ii < 8; ++ii)
        av[nxt][ii] = *(const float4*)&a[(ty + 8 * ii) * PAD + k2];
#pragma unroll
      for (int kk = 0; kk < 4; ++kk)
        bv[nxt][kk] = *(const float4*)&b[(kc * 4 + 4 + kk) * PAD + n0];
    }
#pragma unroll
    for (int kk = 0; kk < 4; ++kk) {
      const float4 bb = bv[cur][kk];
#pragma unroll
      for (int ii = 0; ii < 8; ++ii) {
        const float s = f4c(av[cur][ii], kk);
        acc[ii].x += s * bb.x; acc[ii].y += s * bb.y;
        acc[ii].z += s * bb.z; acc[ii].w += s * bb.w;
      }
    }
  }
#pragma unroll
  for (int ii = 0; ii < 8; ++ii)
    *(float4*)&c[(ty + 8 * ii) * PAD + n0] = acc[ii];
}

// global row-major 64x64 -> LDS pad-68
template <int NT>
__device__ __forceinline__ void stage(const float* __restrict__ g,
                                      float* __restrict__ l, int tid) {
  for (int e = tid; e < 1024; e += NT) {
    const int row = e >> 4, c4 = (e & 15) << 2;
    *(float4*)&l[row * PAD + c4] = *(const float4*)&g[row * 64 + c4];
  }
}

// LDS pad-68 -> global row-major 64x64 (scaled)
template <int NT>
__device__ __forceinline__ void unstage(const float* __restrict__ l,
                                        float* __restrict__ g, int tid,
                                        float scale) {
  for (int e = tid; e < 1024; e += NT) {
    const int row = e >> 4, c4 = (e & 15) << 2;
    float4 v = *(const float4*)&l[row * PAD + c4];
    v.x *= scale; v.y *= scale; v.z *= scale; v.w *= scale;
    *(float4*)&g[row * 64 + c4] = v;
  }
}

// ---------------------------------------------------------------------------
// K1: one block, 128 threads.
// dt; recursive-doubling inverse of lower-triangular M = I - (dt/2)A
// (diag >= 1.05, no pivoting); A_bar = 2*Minv - I; 11 pipelined squarings.
// ---------------------------------------------------------------------------
__global__ __launch_bounds__(128) void k_setup(const float* __restrict__ A,
                                               const float* __restrict__ logdt,
                                               float* __restrict__ ws) {
  __shared__ float Msh[64 * 65];
  __shared__ float Tm[64 * 65];
  __shared__ float tmpb[1024];
  __shared__ __align__(16) float bufA[64 * PAD];
  __shared__ __align__(16) float bufB[64 * PAD];
  const int tid = threadIdx.x;
  const float dt = expf(logdt[0]);
  const float hdt = 0.5f * dt;
  if (tid == 0) ws[WS_DT] = dt;

  for (int idx = tid; idx < 4096; idx += 128) {
    const int i = idx >> 6, j = idx & 63;
    Msh[i * 65 + j] = ((i == j) ? 1.f : 0.f) - hdt * A[idx];
    Tm[i * 65 + j] = 0.f;
  }
  __syncthreads();
  if (tid < 64) Tm[tid * 65 + tid] = 1.0f / Msh[tid * 65 + tid];
  __syncthreads();

  // Recursive doubling: T21 = -T22 * M21 * T11 per diagonal block pair.
  for (int lb = 0; lb < 6; ++lb) {
    const int b = 1 << lb;
    const int E = 32 * b;
    for (int e = tid; e < E; e += 128) {
      const int rem = e & (b * b - 1);
      const int p = e >> (2 * lb);
      const int i = rem >> lb, j = rem & (b - 1);
      const int c0 = p << (lb + 1), r0 = c0 + b;
      float s = 0.f;
      for (int k = 0; k < b; ++k)
        s += Msh[(r0 + i) * 65 + c0 + k] * Tm[(c0 + k) * 65 + c0 + j];
      tmpb[e] = s;
    }
    __syncthreads();
    for (int e = tid; e < E; e += 128) {
      const int rem = e & (b * b - 1);
      const int p = e >> (2 * lb);
      const int i = rem >> lb, j = rem & (b - 1);
      const int c0 = p << (lb + 1), r0 = c0 + b;
      float s = 0.f;
      const float* tp = &tmpb[e - rem];
      for (int k = 0; k < b; ++k)
        s += Tm[(r0 + i) * 65 + r0 + k] * tp[k * b + j];
      Tm[(r0 + i) * 65 + c0 + j] = -s;
    }
    __syncthreads();
  }

  // Minv^T to ws (for B_bar).
  for (int idx = tid; idx < 4096; idx += 128) {
    const int k = idx >> 6, n = idx & 63;
    ws[WS_MINVT + idx] = Tm[n * 65 + k];
  }
  // A_bar = 2*Minv - I -> bufA (padded) and ws S_0.
  for (int idx = tid; idx < 4096; idx += 128) {
    const int i = idx >> 6, j = idx & 63;
    const float v = 2.f * Tm[i * 65 + j] - ((i == j) ? 1.f : 0.f);
    bufA[i * PAD + j] = v;
    ws[WS_S + idx] = v;
  }
  __syncthreads();

  float* cur = bufA;
  float* nxt = bufB;
  for (int sj = 1; sj < 12; ++sj) {
    mm64_128p(cur, cur, nxt, tid);
    __syncthreads();
    unstage<128>(nxt, ws + WS_S + sj * 4096, tid, 1.f);
    float* t = cur; cur = nxt; nxt = t;
  }
}

// ---------------------------------------------------------------------------
// K2: 144 blocks x 128.
//   p in [0,64):    G_r  = prod S_j over set bits of r   (row-major)
//   p in [64,128):  H_q^T (transposed store)
//   p in [128,144): B_bar chunk: dt * B_chunk @ Minv^T
// ---------------------------------------------------------------------------
__global__ __launch_bounds__(128) void k_powers(const float* __restrict__ Bg,
                                                float* __restrict__ ws) {
  __shared__ __align__(16) float ra[64 * PAD];
  __shared__ __align__(16) float rb[64 * PAD];
  __shared__ __align__(16) float sm[64 * PAD];
  const int p = blockIdx.x, tid = threadIdx.x;

  if (p < 128) {
    const int chain = p >> 6, r = p & 63;
    float* cur = ra;
    float* nxt = rb;
    if (r == 0) {
      for (int idx = tid; idx < 4096; idx += 128) {
        const int i = idx >> 6, j = idx & 63;
        cur[i * PAD + j] = (i == j) ? 1.f : 0.f;
      }
    } else {
      const int j0 = __ffs(r) - 1;
      stage<128>(ws + WS_S + (chain * 6 + j0) * 4096, cur, tid);
      for (int j = j0 + 1; j < 6; ++j) {
        if ((r >> j) & 1) {  // block-uniform branch
          __syncthreads();
          stage<128>(ws + WS_S + (chain * 6 + j) * 4096, sm, tid);
          __syncthreads();
          mm64_128p(cur, sm, nxt, tid);
          __syncthreads();
          float* t = cur; cur = nxt; nxt = t;
        }
      }
    }
    __syncthreads();
    if (chain == 0) {
      unstage<128>(cur, ws + WS_G + r * 4096, tid, 1.f);
    } else {
      float* HT = ws + WS_HT + r * 4096;
      for (int idx = tid; idx < 4096; idx += 128) {
        const int k = idx >> 6, n = idx & 63;
        HT[idx] = cur[n * PAD + k];
      }
    }
  } else {
    const int d0 = (p - 128) * 64;
    stage<128>(ws + WS_MINVT, sm, tid);
    stage<128>(Bg + d0 * 64, ra, tid);
    __syncthreads();
    mm64_128p(ra, sm, rb, tid);
    __syncthreads();
    unstage<128>(rb, ws + WS_BBAR + d0 * 64, tid, ws[WS_DT]);
  }
}

// ---------------------------------------------------------------------------
// K3: 2048 blocks x 256. Block = (chain, rr, dch).
// chain0: W[d0.., rr, :] = C_chunk @ G_rr; chain1: X = Bbar_chunk @ H_rr^T.
// Thread tile 4x4 (rows ty+16*ii interleaved -> av banks 4*ty spread;
// bv 16-lane broadcast spans). VGPR ~70, LDS 34.8KB -> 4 blocks/CU, 16 w/CU.
// ---------------------------------------------------------------------------
__global__ __launch_bounds__(256) void k_expand(const float* __restrict__ Cg,
                                                float* __restrict__ ws) {
  __shared__ __align__(16) float matL[64 * PAD];
  __shared__ __align__(16) float srcL[64 * PAD];
  const int p = blockIdx.x, tid = threadIdx.x;
  const int chain = p >> 10, rr = (p >> 4) & 63, dch = p & 15;
  const int d0 = dch * 64;
  const float* msrc = ws + (chain ? WS_HT : WS_G) + rr * 4096;
  const float* vsrc = chain ? (ws + WS_BBAR + d0 * 64) : (Cg + d0 * 64);

  stage<256>(msrc, matL, tid);
  stage<256>(vsrc, srcL, tid);
  __syncthreads();

  const int tx = tid & 15, ty = tid >> 4;  // n0 = 4*tx, rows = ty + 16*ii
  const int n0 = 4 * tx;
  float4 acc[4];
#pragma unroll
  for (int ii = 0; ii < 4; ++ii) acc[ii] = make_float4(0.f, 0.f, 0.f, 0.f);
  for (int k = 0; k < 64; k += 4) {
    float4 av[4], bv[4];
#pragma unroll
    for (int ii = 0; ii < 4; ++ii)
      av[ii] = *(const float4*)&srcL[(ty + 16 * ii) * PAD + k];
#pragma unroll
    for (int kk = 0; kk < 4; ++kk)
      bv[kk] = *(const float4*)&matL[(k + kk) * PAD + n0];
#pragma unroll
    for (int kk = 0; kk < 4; ++kk) {
      const float4 bb = bv[kk];
#pragma unroll
      for (int ii = 0; ii < 4; ++ii) {
        const float s = f4c(av[ii], kk);
        acc[ii].x += s * bb.x; acc[ii].y += s * bb.y;
        acc[ii].z += s * bb.z; acc[ii].w += s * bb.w;
      }
    }
  }
  float* dst = ws + (chain ? WS_X : WS_W);
#pragma unroll
  for (int ii = 0; ii < 4; ++ii)
    *(float4*)&dst[(d0 + ty + 16 * ii) * 4096 + rr * 64 + n0] = acc[ii];
}

// ---------------------------------------------------------------------------
// K4: 1024 blocks x 256, one block per d.
// K[q*64+r] = sum_n W[r,n] X[q,n]; r = rt+16*ii (2-way/broadcast reads,
// 64B store segments filled by adjacent ii), q = qb+16*jj (broadcast reads).
// Thread tile 4x4, VGPR ~70, no manual prefetch. + D[d] at l==0.
// ---------------------------------------------------------------------------
__global__ __launch_bounds__(256) void k_contract(const float* __restrict__ Dg,
                                                  const float* __restrict__ ws,
                                                  float* __restrict__ out) {
  __shared__ __align__(16) float Wl[64 * PAD];
  __shared__ __align__(16) float Xl[64 * PAD];
  const int d = blockIdx.x, tid = threadIdx.x;
  stage<256>(ws + WS_W + d * 4096, Wl, tid);
  stage<256>(ws + WS_X + d * 4096, Xl, tid);
  __syncthreads();

  const int rt = tid & 15, qb = tid >> 4;
  float acc[4][4];
#pragma unroll
  for (int ii = 0; ii < 4; ++ii)
#pragma unroll
    for (int jj = 0; jj < 4; ++jj) acc[ii][jj] = 0.f;

  for (int nn = 0; nn < 64; nn += 4) {
    float4 av[4], xv[4];
#pragma unroll
    for (int ii = 0; ii < 4; ++ii)
      av[ii] = *(const float4*)&Wl[(rt + 16 * ii) * PAD + nn];
#pragma unroll
    for (int jj = 0; jj < 4; ++jj)
      xv[jj] = *(const float4*)&Xl[(qb + 16 * jj) * PAD + nn];
#pragma unroll
    for (int jj = 0; jj < 4; ++jj) {
      const float4 x = xv[jj];
#pragma unroll
      for (int ii = 0; ii < 4; ++ii) {
        const float4 w = av[ii];
        acc[ii][jj] += w.x * x.x + w.y * x.y + w.z * x.z + w.w * x.w;
      }
    }
  }
  const float dval = Dg[d];
  float* od = out + d * 4096;
#pragma unroll
  for (int jj = 0; jj < 4; ++jj) {
#pragma unroll
    for (int ii = 0; ii < 4; ++ii) {
      const int q = qb + 16 * jj, r = rt + 16 * ii;
      const int l = q * 64 + r;
      od[l] = acc[ii][jj] + ((l == 0) ? dval : 0.f);
    }
  }
}

extern "C" void kernel_launch(void* const* d_in, const int* in_sizes, int n_in,
                              void* d_out, int out_size, void* d_ws, size_t ws_size,
                              hipStream_t stream) {
  const float* A     = (const float*)d_in[0];  // A_ct 64x64
  const float* B     = (const float*)d_in[1];  // 1024x64
  const float* C     = (const float*)d_in[2];  // 1024x64
  const float* Dv    = (const float*)d_in[3];  // 1024
  const float* logdt = (const float*)d_in[4];  // scalar
  float* ws  = (float*)d_ws;                   // 36.2 MB
  float* out = (float*)d_out;                  // 1024*4096 fp32

  hipLaunchKernelGGL(k_setup,    dim3(1),    dim3(128), 0, stream, A, logdt, ws);
  hipLaunchKernelGGL(k_powers,   dim3(144),  dim3(128), 0, stream, B, ws);
  hipLaunchKernelGGL(k_expand,   dim3(2048), dim3(256), 0, stream, C, ws);
  hipLaunchKernelGGL(k_contract, dim3(1024), dim3(256), 0, stream, Dv, ws, out);
}

// Round 5
// 165.036 us; speedup vs baseline: 1.8665x; 1.2408x over previous
//
#include <hip/hip_runtime.h>
#include <math.h>

// HiPPO-LegS kernel: K[d, l] = C[d]^T A_bar^l B_bar[d], D=1024, N=64, L=4096.
// l = 64q + r decomposition; G_r = A_bar^r, H_q = (A_bar^64)^q via squarings
// S_j = A_bar^(2^j), j=0..11.
// Round 5: split-K 256-thread mm (4 waves, LDS partial-reduce) for the
// occupancy-starved setup/powers kernels (R4 showed 2-wave mm is latency-
// bound at ~17% VALU of its CU); k_expand to 8x4 tiles / 2 rr per block
// (fewer LDS insts per FMA — ds_read cost is per-inst, broadcast wastes pipe).

#define PAD 68

// ws layout (float offsets). Total 9,031,744 floats = 36.1 MB.
#define WS_DT     0
#define WS_S      64                       // 12 matrices of 4096
#define WS_MINVT  (WS_S + 12*4096)         // 49216
#define WS_BBAR   (WS_MINVT + 4096)        // 53312, 1024x64
#define WS_G      (WS_BBAR + 1024*64)      // 118848, 64 x 4096 (G_r row-major [k][n])
#define WS_HT     (WS_G + 64*4096)         // 380992, 64 x 4096 (H_q^T: [k][n] = H[n][k])
#define WS_W      (WS_HT + 64*4096)        // 643136, [d][r][n]
#define WS_X      (WS_W + 1024*4096)       // 4837440, [d][q][n]

__device__ __forceinline__ float f4c(const float4 v, int kk) {
  return kk == 0 ? v.x : kk == 1 ? v.y : kk == 2 ? v.z : v.w;
}

// 64x64x64 matmul c = a @ b (LDS pad-68 operands/output), 256 threads.
// Split-K: plane = tid>>7 takes k in [32*plane, 32*plane+32), 8x4 tiles.
// plane 1 writes partials to red; plane 0 adds and stores c.
// Contains one internal __syncthreads (uniform). Caller must barrier before
// reading c. VGPR ~110: no spill.
__device__ __forceinline__ void mm64_256sk(const float* __restrict__ a,
                                           const float* __restrict__ b,
                                           float* __restrict__ c,
                                           float* __restrict__ red, int tid) {
  const int plane = tid >> 7, pt = tid & 127;
  const int tx = pt & 15, ty = pt >> 4;
  const int n0 = 4 * tx, k0 = 32 * plane;
  float4 acc[8];
#pragma unroll
  for (int ii = 0; ii < 8; ++ii) acc[ii] = make_float4(0.f, 0.f, 0.f, 0.f);
#pragma unroll
  for (int kc = 0; kc < 8; ++kc) {
    const int k = k0 + kc * 4;
    float4 av[8], bv[4];
#pragma unroll
    for (int ii = 0; ii < 8; ++ii)
      av[ii] = *(const float4*)&a[(ty + 8 * ii) * PAD + k];
#pragma unroll
    for (int kk = 0; kk < 4; ++kk)
      bv[kk] = *(const float4*)&b[(k + kk) * PAD + n0];
#pragma unroll
    for (int kk = 0; kk < 4; ++kk) {
      const float4 bb = bv[kk];
#pragma unroll
      for (int ii = 0; ii < 8; ++ii) {
        const float s = f4c(av[ii], kk);
        acc[ii].x += s * bb.x; acc[ii].y += s * bb.y;
        acc[ii].z += s * bb.z; acc[ii].w += s * bb.w;
      }
    }
  }
  if (plane == 1) {
#pragma unroll
    for (int ii = 0; ii < 8; ++ii)
      *(float4*)&red[(ty + 8 * ii) * PAD + n0] = acc[ii];
  }
  __syncthreads();
  if (plane == 0) {
#pragma unroll
    for (int ii = 0; ii < 8; ++ii) {
      const float4 r4 = *(const float4*)&red[(ty + 8 * ii) * PAD + n0];
      acc[ii].x += r4.x; acc[ii].y += r4.y; acc[ii].z += r4.z; acc[ii].w += r4.w;
      *(float4*)&c[(ty + 8 * ii) * PAD + n0] = acc[ii];
    }
  }
}

// global row-major 64x64 -> LDS pad-68
template <int NT>
__device__ __forceinline__ void stage(const float* __restrict__ g,
                                      float* __restrict__ l, int tid) {
  for (int e = tid; e < 1024; e += NT) {
    const int row = e >> 4, c4 = (e & 15) << 2;
    *(float4*)&l[row * PAD + c4] = *(const float4*)&g[row * 64 + c4];
  }
}

// LDS pad-68 -> global row-major 64x64 (scaled)
template <int NT>
__device__ __forceinline__ void unstage(const float* __restrict__ l,
                                        float* __restrict__ g, int tid,
                                        float scale) {
  for (int e = tid; e < 1024; e += NT) {
    const int row = e >> 4, c4 = (e & 15) << 2;
    float4 v = *(const float4*)&l[row * PAD + c4];
    v.x *= scale; v.y *= scale; v.z *= scale; v.w *= scale;
    *(float4*)&g[row * 64 + c4] = v;
  }
}

// ---------------------------------------------------------------------------
// K1: one block, 256 threads.
// dt; recursive-doubling inverse of lower-triangular M = I - (dt/2)A
// (diag >= 1.05, no pivoting); A_bar = 2*Minv - I; 11 split-K squarings.
// LDS: 2*16.6 + 4 + 3*17.4 = 89.7 KB.
// ---------------------------------------------------------------------------
__global__ __launch_bounds__(256) void k_setup(const float* __restrict__ A,
                                               const float* __restrict__ logdt,
                                               float* __restrict__ ws) {
  __shared__ float Msh[64 * 65];
  __shared__ float Tm[64 * 65];
  __shared__ float tmpb[1024];
  __shared__ __align__(16) float bufA[64 * PAD];
  __shared__ __align__(16) float bufB[64 * PAD];
  __shared__ __align__(16) float redb[64 * PAD];
  const int tid = threadIdx.x;
  const float dt = expf(logdt[0]);
  const float hdt = 0.5f * dt;
  if (tid == 0) ws[WS_DT] = dt;

  for (int idx = tid; idx < 4096; idx += 256) {
    const int i = idx >> 6, j = idx & 63;
    Msh[i * 65 + j] = ((i == j) ? 1.f : 0.f) - hdt * A[idx];
    Tm[i * 65 + j] = 0.f;
  }
  __syncthreads();
  if (tid < 64) Tm[tid * 65 + tid] = 1.0f / Msh[tid * 65 + tid];
  __syncthreads();

  // Recursive doubling: T21 = -T22 * M21 * T11 per diagonal block pair.
  for (int lb = 0; lb < 6; ++lb) {
    const int b = 1 << lb;
    const int E = 32 * b;
    for (int e = tid; e < E; e += 256) {
      const int rem = e & (b * b - 1);
      const int p = e >> (2 * lb);
      const int i = rem >> lb, j = rem & (b - 1);
      const int c0 = p << (lb + 1), r0 = c0 + b;
      float s = 0.f;
      for (int k = 0; k < b; ++k)
        s += Msh[(r0 + i) * 65 + c0 + k] * Tm[(c0 + k) * 65 + c0 + j];
      tmpb[e] = s;
    }
    __syncthreads();
    for (int e = tid; e < E; e += 256) {
      const int rem = e & (b * b - 1);
      const int p = e >> (2 * lb);
      const int i = rem >> lb, j = rem & (b - 1);
      const int c0 = p << (lb + 1), r0 = c0 + b;
      float s = 0.f;
      const float* tp = &tmpb[e - rem];
      for (int k = 0; k < b; ++k)
        s += Tm[(r0 + i) * 65 + r0 + k] * tp[k * b + j];
      Tm[(r0 + i) * 65 + c0 + j] = -s;
    }
    __syncthreads();
  }

  // Minv^T to ws (for B_bar).
  for (int idx = tid; idx < 4096; idx += 256) {
    const int k = idx >> 6, n = idx & 63;
    ws[WS_MINVT + idx] = Tm[n * 65 + k];
  }
  // A_bar = 2*Minv - I -> bufA (padded) and ws S_0.
  for (int idx = tid; idx < 4096; idx += 256) {
    const int i = idx >> 6, j = idx & 63;
    const float v = 2.f * Tm[i * 65 + j] - ((i == j) ? 1.f : 0.f);
    bufA[i * PAD + j] = v;
    ws[WS_S + idx] = v;
  }
  __syncthreads();

  float* cur = bufA;
  float* nxt = bufB;
  for (int sj = 1; sj < 12; ++sj) {
    mm64_256sk(cur, cur, nxt, redb, tid);
    __syncthreads();
    unstage<256>(nxt, ws + WS_S + sj * 4096, tid, 1.f);
    float* t = cur; cur = nxt; nxt = t;
  }
}

// ---------------------------------------------------------------------------
// K2: 144 blocks x 256.
//   p in [0,64):    G_r  = prod S_j over set bits of r   (row-major)
//   p in [64,128):  H_q^T (transposed store)
//   p in [128,144): B_bar chunk: dt * B_chunk @ Minv^T
// LDS 69.6 KB -> <=2 blocks/CU (144 blocks spread over 256 CUs: 1 each).
// ---------------------------------------------------------------------------
__global__ __launch_bounds__(256) void k_powers(const float* __restrict__ Bg,
                                                float* __restrict__ ws) {
  __shared__ __align__(16) float ra[64 * PAD];
  __shared__ __align__(16) float rb[64 * PAD];
  __shared__ __align__(16) float sm[64 * PAD];
  __shared__ __align__(16) float redb[64 * PAD];
  const int p = blockIdx.x, tid = threadIdx.x;

  if (p < 128) {
    const int chain = p >> 6, r = p & 63;
    float* cur = ra;
    float* nxt = rb;
    if (r == 0) {
      for (int idx = tid; idx < 4096; idx += 256) {
        const int i = idx >> 6, j = idx & 63;
        cur[i * PAD + j] = (i == j) ? 1.f : 0.f;
      }
    } else {
      const int j0 = __ffs(r) - 1;
      stage<256>(ws + WS_S + (chain * 6 + j0) * 4096, cur, tid);
      for (int j = j0 + 1; j < 6; ++j) {
        if ((r >> j) & 1) {  // block-uniform branch
          __syncthreads();
          stage<256>(ws + WS_S + (chain * 6 + j) * 4096, sm, tid);
          __syncthreads();
          mm64_256sk(cur, sm, nxt, redb, tid);
          __syncthreads();
          float* t = cur; cur = nxt; nxt = t;
        }
      }
    }
    __syncthreads();
    if (chain == 0) {
      unstage<256>(cur, ws + WS_G + r * 4096, tid, 1.f);
    } else {
      float* HT = ws + WS_HT + r * 4096;
      for (int idx = tid; idx < 4096; idx += 256) {
        const int k = idx >> 6, n = idx & 63;
        HT[idx] = cur[n * PAD + k];
      }
    }
  } else {
    const int d0 = (p - 128) * 64;
    stage<256>(ws + WS_MINVT, sm, tid);
    stage<256>(Bg + d0 * 64, ra, tid);
    __syncthreads();
    mm64_256sk(ra, sm, rb, redb, tid);
    __syncthreads();
    unstage<256>(rb, ws + WS_BBAR + d0 * 64, tid, ws[WS_DT]);
  }
}

// ---------------------------------------------------------------------------
// K3: 1024 blocks x 256. Block = (chain, rpair, dch); plane = tid>>7 owns
// rr = 2*rpair+plane. 8x4 tiles (12 LDS insts per 128 FMA insts).
// chain0: W[d0.., rr, :] = C_chunk @ G_rr; chain1: X = Bbar_chunk @ H_rr^T.
// LDS 52.2 KB -> 3 blocks/CU = 12 waves/CU. VGPR ~100.
// ---------------------------------------------------------------------------
__global__ __launch_bounds__(256) void k_expand(const float* __restrict__ Cg,
                                                float* __restrict__ ws) {
  __shared__ __align__(16) float matL[2][64 * PAD];
  __shared__ __align__(16) float srcL[64 * PAD];
  const int p = blockIdx.x, tid = threadIdx.x;
  const int chain = p >> 9, rpair = (p >> 4) & 31, dch = p & 15;
  const int plane = tid >> 7, pt = tid & 127;
  const int d0 = dch * 64;
  const int rr = rpair * 2 + plane;
  const float* msrc = ws + (chain ? WS_HT : WS_G) + rr * 4096;
  const float* vsrc = chain ? (ws + WS_BBAR + d0 * 64) : (Cg + d0 * 64);

  for (int e = pt; e < 1024; e += 128) {  // each plane stages its own mat
    const int row = e >> 4, c4 = (e & 15) << 2;
    *(float4*)&matL[plane][row * PAD + c4] = *(const float4*)&msrc[row * 64 + c4];
  }
  stage<256>(vsrc, srcL, tid);
  __syncthreads();

  const int tx = pt & 15, ty = pt >> 4;  // n0 = 4*tx, rows = ty + 8*ii
  const int n0 = 4 * tx;
  const float* mw = matL[plane];
  float4 acc[8];
#pragma unroll
  for (int ii = 0; ii < 8; ++ii) acc[ii] = make_float4(0.f, 0.f, 0.f, 0.f);
  for (int k = 0; k < 64; k += 4) {
    float4 av[8], bv[4];
#pragma unroll
    for (int ii = 0; ii < 8; ++ii)
      av[ii] = *(const float4*)&srcL[(ty + 8 * ii) * PAD + k];
#pragma unroll
    for (int kk = 0; kk < 4; ++kk)
      bv[kk] = *(const float4*)&mw[(k + kk) * PAD + n0];
#pragma unroll
    for (int kk = 0; kk < 4; ++kk) {
      const float4 bb = bv[kk];
#pragma unroll
      for (int ii = 0; ii < 8; ++ii) {
        const float s = f4c(av[ii], kk);
        acc[ii].x += s * bb.x; acc[ii].y += s * bb.y;
        acc[ii].z += s * bb.z; acc[ii].w += s * bb.w;
      }
    }
  }
  float* dst = ws + (chain ? WS_X : WS_W);
#pragma unroll
  for (int ii = 0; ii < 8; ++ii)
    *(float4*)&dst[(d0 + ty + 8 * ii) * 4096 + rr * 64 + n0] = acc[ii];
}

// ---------------------------------------------------------------------------
// K4: 1024 blocks x 256, one block per d (unchanged from R4 — control).
// K[q*64+r] = sum_n W[r,n] X[q,n]; 4x4 tiles. + D[d] at l==0.
// ---------------------------------------------------------------------------
__global__ __launch_bounds__(256) void k_contract(const float* __restrict__ Dg,
                                                  const float* __restrict__ ws,
                                                  float* __restrict__ out) {
  __shared__ __align__(16) float Wl[64 * PAD];
  __shared__ __align__(16) float Xl[64 * PAD];
  const int d = blockIdx.x, tid = threadIdx.x;
  stage<256>(ws + WS_W + d * 4096, Wl, tid);
  stage<256>(ws + WS_X + d * 4096, Xl, tid);
  __syncthreads();

  const int rt = tid & 15, qb = tid >> 4;
  float acc[4][4];
#pragma unroll
  for (int ii = 0; ii < 4; ++ii)
#pragma unroll
    for (int jj = 0; jj < 4; ++jj) acc[ii][jj] = 0.f;

  for (int nn = 0; nn < 64; nn += 4) {
    float4 av[4], xv[4];
#pragma unroll
    for (int ii = 0; ii < 4; ++ii)
      av[ii] = *(const float4*)&Wl[(rt + 16 * ii) * PAD + nn];
#pragma unroll
    for (int jj = 0; jj < 4; ++jj)
      xv[jj] = *(const float4*)&Xl[(qb + 16 * jj) * PAD + nn];
#pragma unroll
    for (int jj = 0; jj < 4; ++jj) {
      const float4 x = xv[jj];
#pragma unroll
      for (int ii = 0; ii < 4; ++ii) {
        const float4 w = av[ii];
        acc[ii][jj] += w.x * x.x + w.y * x.y + w.z * x.z + w.w * x.w;
      }
    }
  }
  const float dval = Dg[d];
  float* od = out + d * 4096;
#pragma unroll
  for (int jj = 0; jj < 4; ++jj) {
#pragma unroll
    for (int ii = 0; ii < 4; ++ii) {
      const int q = qb + 16 * jj, r = rt + 16 * ii;
      const int l = q * 64 + r;
      od[l] = acc[ii][jj] + ((l == 0) ? dval : 0.f);
    }
  }
}

extern "C" void kernel_launch(void* const* d_in, const int* in_sizes, int n_in,
                              void* d_out, int out_size, void* d_ws, size_t ws_size,
                              hipStream_t stream) {
  const float* A     = (const float*)d_in[0];  // A_ct 64x64
  const float* B     = (const float*)d_in[1];  // 1024x64
  const float* C     = (const float*)d_in[2];  // 1024x64
  const float* Dv    = (const float*)d_in[3];  // 1024
  const float* logdt = (const float*)d_in[4];  // scalar
  float* ws  = (float*)d_ws;                   // 36.2 MB
  float* out = (float*)d_out;                  // 1024*4096 fp32

  hipLaunchKernelGGL(k_setup,    dim3(1),    dim3(256), 0, stream, A, logdt, ws);
  hipLaunchKernelGGL(k_powers,   dim3(144),  dim3(256), 0, stream, B, ws);
  hipLaunchKernelGGL(k_expand,   dim3(1024), dim3(256), 0, stream, C, ws);
  hipLaunchKernelGGL(k_contract, dim3(1024), dim3(256), 0, stream, Dv, ws, out);
}

// Round 6
// 157.288 us; speedup vs baseline: 1.9584x; 1.0493x over previous
//
#include <hip/hip_runtime.h>
#include <math.h>

// HiPPO-LegS kernel: K[d, l] = C[d]^T A_bar^l B_bar[d], D=1024, N=64, L=4096.
// l = 64q + r decomposition; G_r = A_bar^r, H_q = (A_bar^64)^q via squarings
// S_j = A_bar^(2^j), j=0..11.
// Round 6: k_contract moved to MFMA (mfma_f32_16x16x32_bf16) with split-bf16
// operands (hi+lo, 3 MFMA terms) — fp32 tile version was LDS-inst bound
// (1 b128 per 8 FMAs); MFMA needs ~1 per 2048 MACs. Other kernels unchanged
// from the passing R5 build (isolation).

#define PAD 68
#define BPAD 72  // bf16 LDS row stride (144 B -> <=2-way bank aliasing)

// ws layout (float offsets). Total 9,031,744 floats = 36.1 MB.
#define WS_DT     0
#define WS_S      64                       // 12 matrices of 4096
#define WS_MINVT  (WS_S + 12*4096)         // 49216
#define WS_BBAR   (WS_MINVT + 4096)        // 53312, 1024x64
#define WS_G      (WS_BBAR + 1024*64)      // 118848, 64 x 4096 (G_r row-major [k][n])
#define WS_HT     (WS_G + 64*4096)         // 380992, 64 x 4096 (H_q^T: [k][n] = H[n][k])
#define WS_W      (WS_HT + 64*4096)        // 643136, [d][r][n]
#define WS_X      (WS_W + 1024*4096)       // 4837440, [d][q][n]

using bf16x8 = __attribute__((ext_vector_type(8))) short;
using f32x4v = __attribute__((ext_vector_type(4))) float;

__device__ __forceinline__ float f4c(const float4 v, int kk) {
  return kk == 0 ? v.x : kk == 1 ? v.y : kk == 2 ? v.z : v.w;
}

// float -> bf16 (RNE) as raw ushort
__device__ __forceinline__ unsigned short f2bf(float x) {
  unsigned u = __builtin_bit_cast(unsigned, x);
  return (unsigned short)((u + 0x7FFFu + ((u >> 16) & 1u)) >> 16);
}
// the bf16-rounded value of x, as float
__device__ __forceinline__ float bfhi(float x) {
  unsigned u = __builtin_bit_cast(unsigned, x);
  unsigned r = (u + 0x7FFFu + ((u >> 16) & 1u)) & 0xFFFF0000u;
  return __builtin_bit_cast(float, r);
}

// 64x64x64 matmul c = a @ b (LDS pad-68 operands/output), 256 threads.
// Split-K: plane = tid>>7 takes k in [32*plane, 32*plane+32), 8x4 tiles.
// plane 1 writes partials to red; plane 0 adds and stores c.
// Contains one internal __syncthreads (uniform). Caller must barrier before
// reading c.
__device__ __forceinline__ void mm64_256sk(const float* __restrict__ a,
                                           const float* __restrict__ b,
                                           float* __restrict__ c,
                                           float* __restrict__ red, int tid) {
  const int plane = tid >> 7, pt = tid & 127;
  const int tx = pt & 15, ty = pt >> 4;
  const int n0 = 4 * tx, k0 = 32 * plane;
  float4 acc[8];
#pragma unroll
  for (int ii = 0; ii < 8; ++ii) acc[ii] = make_float4(0.f, 0.f, 0.f, 0.f);
#pragma unroll
  for (int kc = 0; kc < 8; ++kc) {
    const int k = k0 + kc * 4;
    float4 av[8], bv[4];
#pragma unroll
    for (int ii = 0; ii < 8; ++ii)
      av[ii] = *(const float4*)&a[(ty + 8 * ii) * PAD + k];
#pragma unroll
    for (int kk = 0; kk < 4; ++kk)
      bv[kk] = *(const float4*)&b[(k + kk) * PAD + n0];
#pragma unroll
    for (int kk = 0; kk < 4; ++kk) {
      const float4 bb = bv[kk];
#pragma unroll
      for (int ii = 0; ii < 8; ++ii) {
        const float s = f4c(av[ii], kk);
        acc[ii].x += s * bb.x; acc[ii].y += s * bb.y;
        acc[ii].z += s * bb.z; acc[ii].w += s * bb.w;
      }
    }
  }
  if (plane == 1) {
#pragma unroll
    for (int ii = 0; ii < 8; ++ii)
      *(float4*)&red[(ty + 8 * ii) * PAD + n0] = acc[ii];
  }
  __syncthreads();
  if (plane == 0) {
#pragma unroll
    for (int ii = 0; ii < 8; ++ii) {
      const float4 r4 = *(const float4*)&red[(ty + 8 * ii) * PAD + n0];
      acc[ii].x += r4.x; acc[ii].y += r4.y; acc[ii].z += r4.z; acc[ii].w += r4.w;
      *(float4*)&c[(ty + 8 * ii) * PAD + n0] = acc[ii];
    }
  }
}

// global row-major 64x64 -> LDS pad-68
template <int NT>
__device__ __forceinline__ void stage(const float* __restrict__ g,
                                      float* __restrict__ l, int tid) {
  for (int e = tid; e < 1024; e += NT) {
    const int row = e >> 4, c4 = (e & 15) << 2;
    *(float4*)&l[row * PAD + c4] = *(const float4*)&g[row * 64 + c4];
  }
}

// LDS pad-68 -> global row-major 64x64 (scaled)
template <int NT>
__device__ __forceinline__ void unstage(const float* __restrict__ l,
                                        float* __restrict__ g, int tid,
                                        float scale) {
  for (int e = tid; e < 1024; e += NT) {
    const int row = e >> 4, c4 = (e & 15) << 2;
    float4 v = *(const float4*)&l[row * PAD + c4];
    v.x *= scale; v.y *= scale; v.z *= scale; v.w *= scale;
    *(float4*)&g[row * 64 + c4] = v;
  }
}

// ---------------------------------------------------------------------------
// K1: one block, 256 threads. (unchanged from R5)
// ---------------------------------------------------------------------------
__global__ __launch_bounds__(256) void k_setup(const float* __restrict__ A,
                                               const float* __restrict__ logdt,
                                               float* __restrict__ ws) {
  __shared__ float Msh[64 * 65];
  __shared__ float Tm[64 * 65];
  __shared__ float tmpb[1024];
  __shared__ __align__(16) float bufA[64 * PAD];
  __shared__ __align__(16) float bufB[64 * PAD];
  __shared__ __align__(16) float redb[64 * PAD];
  const int tid = threadIdx.x;
  const float dt = expf(logdt[0]);
  const float hdt = 0.5f * dt;
  if (tid == 0) ws[WS_DT] = dt;

  for (int idx = tid; idx < 4096; idx += 256) {
    const int i = idx >> 6, j = idx & 63;
    Msh[i * 65 + j] = ((i == j) ? 1.f : 0.f) - hdt * A[idx];
    Tm[i * 65 + j] = 0.f;
  }
  __syncthreads();
  if (tid < 64) Tm[tid * 65 + tid] = 1.0f / Msh[tid * 65 + tid];
  __syncthreads();

  for (int lb = 0; lb < 6; ++lb) {
    const int b = 1 << lb;
    const int E = 32 * b;
    for (int e = tid; e < E; e += 256) {
      const int rem = e & (b * b - 1);
      const int p = e >> (2 * lb);
      const int i = rem >> lb, j = rem & (b - 1);
      const int c0 = p << (lb + 1), r0 = c0 + b;
      float s = 0.f;
      for (int k = 0; k < b; ++k)
        s += Msh[(r0 + i) * 65 + c0 + k] * Tm[(c0 + k) * 65 + c0 + j];
      tmpb[e] = s;
    }
    __syncthreads();
    for (int e = tid; e < E; e += 256) {
      const int rem = e & (b * b - 1);
      const int p = e >> (2 * lb);
      const int i = rem >> lb, j = rem & (b - 1);
      const int c0 = p << (lb + 1), r0 = c0 + b;
      float s = 0.f;
      const float* tp = &tmpb[e - rem];
      for (int k = 0; k < b; ++k)
        s += Tm[(r0 + i) * 65 + r0 + k] * tp[k * b + j];
      Tm[(r0 + i) * 65 + c0 + j] = -s;
    }
    __syncthreads();
  }

  for (int idx = tid; idx < 4096; idx += 256) {
    const int k = idx >> 6, n = idx & 63;
    ws[WS_MINVT + idx] = Tm[n * 65 + k];
  }
  for (int idx = tid; idx < 4096; idx += 256) {
    const int i = idx >> 6, j = idx & 63;
    const float v = 2.f * Tm[i * 65 + j] - ((i == j) ? 1.f : 0.f);
    bufA[i * PAD + j] = v;
    ws[WS_S + idx] = v;
  }
  __syncthreads();

  float* cur = bufA;
  float* nxt = bufB;
  for (int sj = 1; sj < 12; ++sj) {
    mm64_256sk(cur, cur, nxt, redb, tid);
    __syncthreads();
    unstage<256>(nxt, ws + WS_S + sj * 4096, tid, 1.f);
    float* t = cur; cur = nxt; nxt = t;
  }
}

// ---------------------------------------------------------------------------
// K2: 144 blocks x 256. (unchanged from R5)
// ---------------------------------------------------------------------------
__global__ __launch_bounds__(256) void k_powers(const float* __restrict__ Bg,
                                                float* __restrict__ ws) {
  __shared__ __align__(16) float ra[64 * PAD];
  __shared__ __align__(16) float rb[64 * PAD];
  __shared__ __align__(16) float sm[64 * PAD];
  __shared__ __align__(16) float redb[64 * PAD];
  const int p = blockIdx.x, tid = threadIdx.x;

  if (p < 128) {
    const int chain = p >> 6, r = p & 63;
    float* cur = ra;
    float* nxt = rb;
    if (r == 0) {
      for (int idx = tid; idx < 4096; idx += 256) {
        const int i = idx >> 6, j = idx & 63;
        cur[i * PAD + j] = (i == j) ? 1.f : 0.f;
      }
    } else {
      const int j0 = __ffs(r) - 1;
      stage<256>(ws + WS_S + (chain * 6 + j0) * 4096, cur, tid);
      for (int j = j0 + 1; j < 6; ++j) {
        if ((r >> j) & 1) {  // block-uniform branch
          __syncthreads();
          stage<256>(ws + WS_S + (chain * 6 + j) * 4096, sm, tid);
          __syncthreads();
          mm64_256sk(cur, sm, nxt, redb, tid);
          __syncthreads();
          float* t = cur; cur = nxt; nxt = t;
        }
      }
    }
    __syncthreads();
    if (chain == 0) {
      unstage<256>(cur, ws + WS_G + r * 4096, tid, 1.f);
    } else {
      float* HT = ws + WS_HT + r * 4096;
      for (int idx = tid; idx < 4096; idx += 256) {
        const int k = idx >> 6, n = idx & 63;
        HT[idx] = cur[n * PAD + k];
      }
    }
  } else {
    const int d0 = (p - 128) * 64;
    stage<256>(ws + WS_MINVT, sm, tid);
    stage<256>(Bg + d0 * 64, ra, tid);
    __syncthreads();
    mm64_256sk(ra, sm, rb, redb, tid);
    __syncthreads();
    unstage<256>(rb, ws + WS_BBAR + d0 * 64, tid, ws[WS_DT]);
  }
}

// ---------------------------------------------------------------------------
// K3: 1024 blocks x 256. (unchanged from R5)
// ---------------------------------------------------------------------------
__global__ __launch_bounds__(256) void k_expand(const float* __restrict__ Cg,
                                                float* __restrict__ ws) {
  __shared__ __align__(16) float matL[2][64 * PAD];
  __shared__ __align__(16) float srcL[64 * PAD];
  const int p = blockIdx.x, tid = threadIdx.x;
  const int chain = p >> 9, rpair = (p >> 4) & 31, dch = p & 15;
  const int plane = tid >> 7, pt = tid & 127;
  const int d0 = dch * 64;
  const int rr = rpair * 2 + plane;
  const float* msrc = ws + (chain ? WS_HT : WS_G) + rr * 4096;
  const float* vsrc = chain ? (ws + WS_BBAR + d0 * 64) : (Cg + d0 * 64);

  for (int e = pt; e < 1024; e += 128) {
    const int row = e >> 4, c4 = (e & 15) << 2;
    *(float4*)&matL[plane][row * PAD + c4] = *(const float4*)&msrc[row * 64 + c4];
  }
  stage<256>(vsrc, srcL, tid);
  __syncthreads();

  const int tx = pt & 15, ty = pt >> 4;
  const int n0 = 4 * tx;
  const float* mw = matL[plane];
  float4 acc[8];
#pragma unroll
  for (int ii = 0; ii < 8; ++ii) acc[ii] = make_float4(0.f, 0.f, 0.f, 0.f);
  for (int k = 0; k < 64; k += 4) {
    float4 av[8], bv[4];
#pragma unroll
    for (int ii = 0; ii < 8; ++ii)
      av[ii] = *(const float4*)&srcL[(ty + 8 * ii) * PAD + k];
#pragma unroll
    for (int kk = 0; kk < 4; ++kk)
      bv[kk] = *(const float4*)&mw[(k + kk) * PAD + n0];
#pragma unroll
    for (int kk = 0; kk < 4; ++kk) {
      const float4 bb = bv[kk];
#pragma unroll
      for (int ii = 0; ii < 8; ++ii) {
        const float s = f4c(av[ii], kk);
        acc[ii].x += s * bb.x; acc[ii].y += s * bb.y;
        acc[ii].z += s * bb.z; acc[ii].w += s * bb.w;
      }
    }
  }
  float* dst = ws + (chain ? WS_X : WS_W);
#pragma unroll
  for (int ii = 0; ii < 8; ++ii)
    *(float4*)&dst[(d0 + ty + 8 * ii) * 4096 + rr * 64 + n0] = acc[ii];
}

// ---------------------------------------------------------------------------
// K4: 1024 blocks x 256, one block per d — MFMA split-bf16.
// K_d[q*64+r] = sum_n X[q,n] W[r,n].  A-operand = X rows (m=q), B = W rows
// (n=r), D: col=lane&15 -> r (coalesced stores), row=quad*4+reg -> q.
// Split: x = hi + lo (bf16 each); D = Ahi*Bhi + Ahi*Blo + Alo*Bhi.
// LDS: 4 bf16 arrays 64x72 = 36.9 KB -> 4 blocks/CU.
// ---------------------------------------------------------------------------
__global__ __launch_bounds__(256) void k_contract(const float* __restrict__ Dg,
                                                  const float* __restrict__ ws,
                                                  float* __restrict__ out) {
  __shared__ __align__(16) unsigned short XhiL[64 * BPAD];
  __shared__ __align__(16) unsigned short XloL[64 * BPAD];
  __shared__ __align__(16) unsigned short WhiL[64 * BPAD];
  __shared__ __align__(16) unsigned short WloL[64 * BPAD];
  const int d = blockIdx.x, tid = threadIdx.x;
  const float* Wg = ws + WS_W + d * 4096;
  const float* Xg = ws + WS_X + d * 4096;

  // Stage + split-convert. Thread covers flat indices j*1024 + 4*tid (b128
  // coalesced); pack 4 hi ushorts -> uint2, one ds_write_b64 per array.
#pragma unroll
  for (int j = 0; j < 4; ++j) {
    const int flat = j * 1024 + tid * 4;
    const int row = flat >> 6, col = flat & 63;
    const float4 wv = *(const float4*)&Wg[flat];
    const float4 xv = *(const float4*)&Xg[flat];
    const int o = row * BPAD + col;
#pragma unroll
    for (int s = 0; s < 2; ++s) {
      const float4 v = s ? xv : wv;
      unsigned short h0 = f2bf(v.x), h1 = f2bf(v.y), h2 = f2bf(v.z), h3 = f2bf(v.w);
      unsigned short l0 = f2bf(v.x - bfhi(v.x)), l1 = f2bf(v.y - bfhi(v.y));
      unsigned short l2 = f2bf(v.z - bfhi(v.z)), l3 = f2bf(v.w - bfhi(v.w));
      uint2 hp, lp;
      hp.x = (unsigned)h0 | ((unsigned)h1 << 16); hp.y = (unsigned)h2 | ((unsigned)h3 << 16);
      lp.x = (unsigned)l0 | ((unsigned)l1 << 16); lp.y = (unsigned)l2 | ((unsigned)l3 << 16);
      *(uint2*)&(s ? XhiL : WhiL)[o] = hp;
      *(uint2*)&(s ? XloL : WloL)[o] = lp;
    }
  }
  __syncthreads();

  const int w = tid >> 6, lane = tid & 63;
  const int lm = lane & 15, quad = lane >> 4;
  const int qrow = 16 * w + lm;     // A-operand m index (= q)
  const int koff = quad * 8;        // A/B-operand k base within 32-chunk

  f32x4v acc[4];
#pragma unroll
  for (int nt = 0; nt < 4; ++nt) { acc[nt][0] = 0.f; acc[nt][1] = 0.f; acc[nt][2] = 0.f; acc[nt][3] = 0.f; }

#pragma unroll
  for (int kc = 0; kc < 64; kc += 32) {
    const bf16x8 ahi = *(const bf16x8*)&XhiL[qrow * BPAD + kc + koff];
    const bf16x8 alo = *(const bf16x8*)&XloL[qrow * BPAD + kc + koff];
#pragma unroll
    for (int nt = 0; nt < 4; ++nt) {
      const int rrow = 16 * nt + lm;  // B-operand n index (= r)
      const bf16x8 bhi = *(const bf16x8*)&WhiL[rrow * BPAD + kc + koff];
      const bf16x8 blo = *(const bf16x8*)&WloL[rrow * BPAD + kc + koff];
      acc[nt] = __builtin_amdgcn_mfma_f32_16x16x32_bf16(ahi, bhi, acc[nt], 0, 0, 0);
      acc[nt] = __builtin_amdgcn_mfma_f32_16x16x32_bf16(ahi, blo, acc[nt], 0, 0, 0);
      acc[nt] = __builtin_amdgcn_mfma_f32_16x16x32_bf16(alo, bhi, acc[nt], 0, 0, 0);
    }
  }

  if (tid == 0) acc[0][0] += Dg[d];  // l==0 (q=0,r=0): wave0, quad0, reg0, lane0

  float* od = out + d * 4096;
#pragma unroll
  for (int nt = 0; nt < 4; ++nt) {
#pragma unroll
    for (int reg = 0; reg < 4; ++reg) {
      const int q = 16 * w + quad * 4 + reg;
      od[q * 64 + 16 * nt + lm] = acc[nt][reg];
    }
  }
}

extern "C" void kernel_launch(void* const* d_in, const int* in_sizes, int n_in,
                              void* d_out, int out_size, void* d_ws, size_t ws_size,
                              hipStream_t stream) {
  const float* A     = (const float*)d_in[0];  // A_ct 64x64
  const float* B     = (const float*)d_in[1];  // 1024x64
  const float* C     = (const float*)d_in[2];  // 1024x64
  const float* Dv    = (const float*)d_in[3];  // 1024
  const float* logdt = (const float*)d_in[4];  // scalar
  float* ws  = (float*)d_ws;                   // 36.2 MB
  float* out = (float*)d_out;                  // 1024*4096 fp32

  hipLaunchKernelGGL(k_setup,    dim3(1),    dim3(256), 0, stream, A, logdt, ws);
  hipLaunchKernelGGL(k_powers,   dim3(144),  dim3(256), 0, stream, B, ws);
  hipLaunchKernelGGL(k_expand,   dim3(1024), dim3(256), 0, stream, C, ws);
  hipLaunchKernelGGL(k_contract, dim3(1024), dim3(256), 0, stream, Dv, ws, out);
}

// Round 7
// 127.928 us; speedup vs baseline: 2.4078x; 1.2295x over previous
//
#include <hip/hip_runtime.h>
#include <math.h>

// HiPPO-LegS kernel: K[d, l] = C[d]^T A_bar^l B_bar[d], D=1024, N=64, L=4096.
// l = 64q + r decomposition; G_r = A_bar^r, H_q = (A_bar^64)^q via squarings
// S_j = A_bar^(2^j), j=0..11.
// Round 7: ALL 64x64x64 products on MFMA (mfma_f32_16x16x32_bf16, split-bf16
// hi/lo 3-term — technique validated by R6 contract). Squaring chain keeps
// state as bf16 hi/lo in A-layout + Bt-layout LDS, written directly from MFMA
// result regs. ws carries pre-split S_j / S_j^T / Minv / Gt / H operands so
// consumers stage with uint4 copies only.

#define BPAD 72  // bf16 LDS row stride in ushorts (144 B)

// ws layout (float offsets).
#define WS_BBAR   16                      // 1024x64 fp32
#define WS_SPL    65552                   // 12 x 8192: [hi|lo|thi|tlo] x 2048 floats
#define WS_MV     (WS_SPL + 12*8192)      // 163856: MvHi 2048, MvLo 2048
#define WS_GT     (WS_MV + 4096)          // 167952: 64 x 4096 (hi 2048 | lo 2048)
#define WS_H      (WS_GT + 64*4096)       // 430096: 64 x 4096 (hi | lo)
#define WS_W      (WS_H + 64*4096)        // 692240: [d][r][n] fp32
#define WS_X      (WS_W + 1024*4096)      // 4886544: [d][q][n] fp32

using bf16x8 = __attribute__((ext_vector_type(8))) short;
using f32x4v = __attribute__((ext_vector_type(4))) float;
typedef unsigned short ushort_t;

__device__ __forceinline__ ushort_t f2bf(float x) {
  unsigned u = __builtin_bit_cast(unsigned, x);
  return (ushort_t)((u + 0x7FFFu + ((u >> 16) & 1u)) >> 16);
}
__device__ __forceinline__ float bfhi(float x) {
  unsigned u = __builtin_bit_cast(unsigned, x);
  unsigned r = (u + 0x7FFFu + ((u >> 16) & 1u)) & 0xFFFF0000u;
  return __builtin_bit_cast(float, r);
}
__device__ __forceinline__ ushort_t* usp(float* ws, int foff) {
  return (ushort_t*)(ws + foff);
}
__device__ __forceinline__ const ushort_t* uspc(const float* ws, int foff) {
  return (const ushort_t*)(ws + foff);
}

// ---- MFMA 64x64x64: D[m][n] = sum_k A[m][k]*Bt[n][k], split-bf16 3-term ----
// A-layout LDS [m][k] (BPAD), Bt-layout LDS [n][k]. Wave w owns m in [16w,16w+16).
__device__ __forceinline__ void mm_frag(const ushort_t* __restrict__ Ah,
                                        const ushort_t* __restrict__ Al,
                                        const ushort_t* __restrict__ Bh,
                                        const ushort_t* __restrict__ Bl,
                                        int w, int lane, f32x4v acc[4]) {
  const int lm = lane & 15, quad = lane >> 4;
  const int ar = (16 * w + lm) * BPAD, ko = quad * 8;
#pragma unroll
  for (int nt = 0; nt < 4; ++nt) { acc[nt][0] = acc[nt][1] = acc[nt][2] = acc[nt][3] = 0.f; }
#pragma unroll
  for (int kc = 0; kc < 64; kc += 32) {
    const bf16x8 ahi = *(const bf16x8*)&Ah[ar + kc + ko];
    const bf16x8 alo = *(const bf16x8*)&Al[ar + kc + ko];
#pragma unroll
    for (int nt = 0; nt < 4; ++nt) {
      const int br = (16 * nt + lm) * BPAD + kc + ko;
      const bf16x8 bhi = *(const bf16x8*)&Bh[br];
      const bf16x8 blo = *(const bf16x8*)&Bl[br];
      acc[nt] = __builtin_amdgcn_mfma_f32_16x16x32_bf16(ahi, bhi, acc[nt], 0, 0, 0);
      acc[nt] = __builtin_amdgcn_mfma_f32_16x16x32_bf16(ahi, blo, acc[nt], 0, 0, 0);
      acc[nt] = __builtin_amdgcn_mfma_f32_16x16x32_bf16(alo, bhi, acc[nt], 0, 0, 0);
    }
  }
}

// D regs -> split bf16 LDS in BOTH layouts (A-layout [m][n-as-k], Bt [n][m]).
__device__ __forceinline__ void dstore_lds(const f32x4v acc[4],
                                           ushort_t* __restrict__ Ah, ushort_t* __restrict__ Al,
                                           ushort_t* __restrict__ Bth, ushort_t* __restrict__ Btl,
                                           int w, int lane) {
  const int lm = lane & 15, quad = lane >> 4;
#pragma unroll
  for (int nt = 0; nt < 4; ++nt) {
    const int n = 16 * nt + lm;
#pragma unroll
    for (int reg = 0; reg < 4; ++reg) {
      const int m = 16 * w + 4 * quad + reg;
      const float x = acc[nt][reg];
      const ushort_t h = f2bf(x), l = f2bf(x - bfhi(x));
      Ah[m * BPAD + n] = h; Al[m * BPAD + n] = l;
      Bth[n * BPAD + m] = h; Btl[n * BPAD + m] = l;
    }
  }
}

// packed 64x64 ushort ws region <-> padded LDS (BPAD), 256 threads
__device__ __forceinline__ void cp_l2w(const ushort_t* __restrict__ l,
                                       ushort_t* __restrict__ g, int tid) {
  for (int e = tid; e < 512; e += 256) {
    const int row = e >> 3, c8 = (e & 7) * 8;
    *(uint4*)&g[row * 64 + c8] = *(const uint4*)&l[row * BPAD + c8];
  }
}
__device__ __forceinline__ void cp_w2l(const ushort_t* __restrict__ g,
                                       ushort_t* __restrict__ l, int tid) {
  for (int e = tid; e < 512; e += 256) {
    const int row = e >> 3, c8 = (e & 7) * 8;
    *(uint4*)&l[row * BPAD + c8] = *(const uint4*)&g[row * 64 + c8];
  }
}

// fp32 global 64x64 -> split bf16 A-layout LDS, 256 threads
__device__ __forceinline__ void split_stage(const float* __restrict__ g,
                                            ushort_t* __restrict__ Ah,
                                            ushort_t* __restrict__ Al, int tid) {
#pragma unroll
  for (int j = 0; j < 4; ++j) {
    const int flat = j * 1024 + tid * 4;
    const int row = flat >> 6, col = flat & 63;
    const float4 v = *(const float4*)&g[flat];
    ushort_t h0 = f2bf(v.x), h1 = f2bf(v.y), h2 = f2bf(v.z), h3 = f2bf(v.w);
    ushort_t l0 = f2bf(v.x - bfhi(v.x)), l1 = f2bf(v.y - bfhi(v.y));
    ushort_t l2 = f2bf(v.z - bfhi(v.z)), l3 = f2bf(v.w - bfhi(v.w));
    uint2 hp, lp;
    hp.x = (unsigned)h0 | ((unsigned)h1 << 16); hp.y = (unsigned)h2 | ((unsigned)h3 << 16);
    lp.x = (unsigned)l0 | ((unsigned)l1 << 16); lp.y = (unsigned)l2 | ((unsigned)l3 << 16);
    *(uint2*)&Ah[row * BPAD + col] = hp;
    *(uint2*)&Al[row * BPAD + col] = lp;
  }
}

#define ARR (64 * BPAD)  // 4608 ushorts per LDS matrix

// ---------------------------------------------------------------------------
// K1: one block, 256 threads. fp32 recursive-doubling inverse of M (lower-tri,
// diag >= 1.05); A_bar = 2*Minv - I; 11 MFMA split-bf16 squarings with state
// held as hi/lo bf16 (A + Bt layouts). Exports per j: S_j, S_j^T (split) and
// Minv rows (split). LDS overlay: 74.2 KB.
// ---------------------------------------------------------------------------
__global__ __launch_bounds__(256) void k_setup(const float* __restrict__ A,
                                               const float* __restrict__ logdt,
                                               float* __restrict__ ws) {
  __shared__ __align__(16) char SM[74240];
  float* Msh = (float*)SM;                    // 64*65 fp32, dead after phase 2
  float* Tm  = (float*)(SM + 16640);          // 64*65 fp32 (becomes Minv)
  float* tmpb = (float*)(SM + 33280);         // 1024 fp32
  ushort_t* ping = (ushort_t*)(SM + 37376);   // 4 arrays of ARR
  ushort_t* pong = (ushort_t*)SM;             // overlays Msh/Tm/tmpb (dead then)
  const int tid = threadIdx.x;
  const int w = tid >> 6, lane = tid & 63;

  // phase 1: build M, invert (fp32, unchanged from R5)
  const float hdt = 0.5f * expf(logdt[0]);
  for (int idx = tid; idx < 4096; idx += 256) {
    const int i = idx >> 6, j = idx & 63;
    Msh[i * 65 + j] = ((i == j) ? 1.f : 0.f) - hdt * A[idx];
    Tm[i * 65 + j] = 0.f;
  }
  __syncthreads();
  if (tid < 64) Tm[tid * 65 + tid] = 1.0f / Msh[tid * 65 + tid];
  __syncthreads();
  for (int lb = 0; lb < 6; ++lb) {
    const int b = 1 << lb;
    const int E = 32 * b;
    for (int e = tid; e < E; e += 256) {
      const int rem = e & (b * b - 1);
      const int p = e >> (2 * lb);
      const int i = rem >> lb, j = rem & (b - 1);
      const int c0 = p << (lb + 1), r0 = c0 + b;
      float s = 0.f;
      for (int k = 0; k < b; ++k)
        s += Msh[(r0 + i) * 65 + c0 + k] * Tm[(c0 + k) * 65 + c0 + j];
      tmpb[e] = s;
    }
    __syncthreads();
    for (int e = tid; e < E; e += 256) {
      const int rem = e & (b * b - 1);
      const int p = e >> (2 * lb);
      const int i = rem >> lb, j = rem & (b - 1);
      const int c0 = p << (lb + 1), r0 = c0 + b;
      float s = 0.f;
      const float* tp = &tmpb[e - rem];
      for (int k = 0; k < b; ++k)
        s += Tm[(r0 + i) * 65 + r0 + k] * tp[k * b + j];
      Tm[(r0 + i) * 65 + c0 + j] = -s;
    }
    __syncthreads();
  }

  // phase 2: exports from Tm (=Minv) + fill ping with A_bar = 2*Minv - I
  {
    ushort_t* MvH = usp(ws, WS_MV);
    ushort_t* MvL = usp(ws, WS_MV + 2048);
    for (int idx = tid; idx < 4096; idx += 256) {
      const int i = idx >> 6, j = idx & 63;
      const float mv = Tm[i * 65 + j];
      MvH[idx] = f2bf(mv); MvL[idx] = f2bf(mv - bfhi(mv));
      const float v = 2.f * mv - ((i == j) ? 1.f : 0.f);
      const ushort_t h = f2bf(v), l = f2bf(v - bfhi(v));
      ping[0 * ARR + i * BPAD + j] = h; ping[1 * ARR + i * BPAD + j] = l;
      ping[2 * ARR + j * BPAD + i] = h; ping[3 * ARR + j * BPAD + i] = l;
    }
  }
  __syncthreads();
  cp_l2w(ping + 0 * ARR, usp(ws, WS_SPL + 0), tid);
  cp_l2w(ping + 1 * ARR, usp(ws, WS_SPL + 2048), tid);
  cp_l2w(ping + 2 * ARR, usp(ws, WS_SPL + 4096), tid);
  cp_l2w(ping + 3 * ARR, usp(ws, WS_SPL + 6144), tid);

  // phase 3: 11 squarings
  ushort_t* cur = ping;
  ushort_t* nxt = pong;
  for (int sj = 1; sj < 12; ++sj) {
    f32x4v acc[4];
    mm_frag(cur, cur + ARR, cur + 2 * ARR, cur + 3 * ARR, w, lane, acc);
    dstore_lds(acc, nxt, nxt + ARR, nxt + 2 * ARR, nxt + 3 * ARR, w, lane);
    __syncthreads();
    const int base = WS_SPL + sj * 8192;
    cp_l2w(nxt + 0 * ARR, usp(ws, base + 0), tid);
    cp_l2w(nxt + 1 * ARR, usp(ws, base + 2048), tid);
    cp_l2w(nxt + 2 * ARR, usp(ws, base + 4096), tid);
    cp_l2w(nxt + 3 * ARR, usp(ws, base + 6144), tid);
    ushort_t* t = cur; cur = nxt; nxt = t;
  }
}

// ---------------------------------------------------------------------------
// K2: 144 blocks x 256.
//  p in [0,64):   Gt_r = (A^r)^T split  (product over set bits, MFMA)
//  p in [64,128): H_q  = A^(64q) split  (row-major)
//  p in [128,144): B_bar chunk = dt * B @ Minv^T (MFMA, fp32 out)
// ---------------------------------------------------------------------------
__global__ __launch_bounds__(256) void k_powers(const float* __restrict__ Bg,
                                                const float* __restrict__ logdt,
                                                float* __restrict__ ws) {
  __shared__ __align__(16) ushort_t SMp[8 * ARR];  // 73.7 KB
  ushort_t* curA = SMp;                 // 2 arrays (hi,lo)
  ushort_t* ponA = SMp + 2 * ARR;       // 2 arrays
  ushort_t* Bst  = SMp + 4 * ARR;       // 2 arrays (staged Bt operand)
  ushort_t* BtO  = SMp + 6 * ARR;       // 2 arrays (transposed result)
  const int p = blockIdx.x, tid = threadIdx.x;
  const int w = tid >> 6, lane = tid & 63;

  if (p < 128) {
    const int chain = p >> 6, r = p & 63;
    ushort_t* dstH = usp(ws, (chain ? WS_H : WS_GT) + r * 4096);
    ushort_t* dstL = usp(ws, (chain ? WS_H : WS_GT) + r * 4096 + 2048);
    if (r == 0) {  // identity
      for (int idx = tid; idx < 4096; idx += 256) {
        const int i = idx >> 6, j = idx & 63;
        dstH[idx] = (i == j) ? (ushort_t)0x3F80 : (ushort_t)0;
        dstL[idx] = 0;
      }
      return;
    }
    const int j0 = __ffs(r) - 1;
    if (r == (1 << j0)) {  // single bit: straight ws->ws copy
      const int sb = WS_SPL + (chain * 6 + j0) * 8192;
      const int src = chain ? sb : (sb + 4096);  // chain0: St, chain1: S
      const uint4* sh = (const uint4*)uspc(ws, src);
      const uint4* sl = (const uint4*)uspc(ws, src + 2048);
      uint4* dh = (uint4*)dstH;
      uint4* dl = (uint4*)dstL;
      for (int e = tid; e < 512; e += 256) { dh[e] = sh[e]; dl[e] = sl[e]; }
      return;
    }
    // multi-bit chain
    {
      const int sb = WS_SPL + (chain * 6 + j0) * 8192;  // S_{j0} row-major split
      cp_w2l(uspc(ws, sb + 0), curA, tid);
      cp_w2l(uspc(ws, sb + 2048), curA + ARR, tid);
    }
    ushort_t* ca = curA;
    ushort_t* na = ponA;
    for (int j = j0 + 1; j < 6; ++j) {
      if ((r >> j) & 1) {  // block-uniform
        __syncthreads();
        const int sb = WS_SPL + (chain * 6 + j) * 8192;
        cp_w2l(uspc(ws, sb + 4096), Bst, tid);        // St_j hi
        cp_w2l(uspc(ws, sb + 6144), Bst + ARR, tid);  // St_j lo
        __syncthreads();
        f32x4v acc[4];
        mm_frag(ca, ca + ARR, Bst, Bst + ARR, w, lane, acc);
        dstore_lds(acc, na, na + ARR, BtO, BtO + ARR, w, lane);
        ushort_t* t = ca; ca = na; na = t;
      }
    }
    __syncthreads();
    if (chain == 0) {  // Gt = (result)^T
      cp_l2w(BtO, dstH, tid);
      cp_l2w(BtO + ARR, dstL, tid);
    } else {           // H = result row-major
      cp_l2w(ca, dstH, tid);
      cp_l2w(ca + ARR, dstL, tid);
    }
  } else {
    // B_bar chunk: dt * B_chunk @ Minv^T. Bt-frag rows = Minv rows.
    const int d0 = (p - 128) * 64;
    const float dtv = expf(logdt[0]);
    split_stage(Bg + d0 * 64, curA, curA + ARR, tid);
    cp_w2l(uspc(ws, WS_MV), Bst, tid);
    cp_w2l(uspc(ws, WS_MV + 2048), Bst + ARR, tid);
    __syncthreads();
    f32x4v acc[4];
    mm_frag(curA, curA + ARR, Bst, Bst + ARR, w, lane, acc);
    const int lm = lane & 15, quad = lane >> 4;
    float* od = ws + WS_BBAR + d0 * 64;
#pragma unroll
    for (int nt = 0; nt < 4; ++nt)
#pragma unroll
      for (int reg = 0; reg < 4; ++reg)
        od[(16 * w + 4 * quad + reg) * 64 + 16 * nt + lm] = dtv * acc[nt][reg];
  }
}

// ---------------------------------------------------------------------------
// K3: 2048 blocks x 256. Block = (chain, rr, dch).
//  chain0: W[d0..][rr][j] = sum_n C[d,n] A^rr[n,j]   (Bt = Gt_rr, pre-split)
//  chain1: X[d0..][rr][j] = sum_k Bbar[d,k] H_rr[j,k] (Bt = H_rr, pre-split)
// LDS 36.9 KB -> 4 blocks/CU.
// ---------------------------------------------------------------------------
__global__ __launch_bounds__(256) void k_expand(const float* __restrict__ Cg,
                                                float* __restrict__ ws) {
  __shared__ __align__(16) ushort_t SMe[4 * ARR];
  ushort_t* Asp = SMe;            // hi, lo
  ushort_t* Bsp = SMe + 2 * ARR;  // hi, lo
  const int p = blockIdx.x, tid = threadIdx.x;
  const int chain = p >> 10, rr = (p >> 4) & 63, dch = p & 15;
  const int w = tid >> 6, lane = tid & 63;
  const int d0 = dch * 64;

  split_stage(chain ? (ws + WS_BBAR + d0 * 64) : (Cg + d0 * 64), Asp, Asp + ARR, tid);
  const int mb = (chain ? WS_H : WS_GT) + rr * 4096;
  cp_w2l(uspc(ws, mb + 0), Bsp, tid);
  cp_w2l(uspc(ws, mb + 2048), Bsp + ARR, tid);
  __syncthreads();

  f32x4v acc[4];
  mm_frag(Asp, Asp + ARR, Bsp, Bsp + ARR, w, lane, acc);

  const int lm = lane & 15, quad = lane >> 4;
  float* dst = ws + (chain ? WS_X : WS_W) + d0 * 4096 + rr * 64;
#pragma unroll
  for (int nt = 0; nt < 4; ++nt)
#pragma unroll
    for (int reg = 0; reg < 4; ++reg)
      dst[(16 * w + 4 * quad + reg) * 4096 + 16 * nt + lm] = acc[nt][reg];
}

// ---------------------------------------------------------------------------
// K4: 1024 blocks x 256, one block per d — MFMA split-bf16 (unchanged R6).
// ---------------------------------------------------------------------------
__global__ __launch_bounds__(256) void k_contract(const float* __restrict__ Dg,
                                                  const float* __restrict__ ws,
                                                  float* __restrict__ out) {
  __shared__ __align__(16) ushort_t XhiL[64 * BPAD];
  __shared__ __align__(16) ushort_t XloL[64 * BPAD];
  __shared__ __align__(16) ushort_t WhiL[64 * BPAD];
  __shared__ __align__(16) ushort_t WloL[64 * BPAD];
  const int d = blockIdx.x, tid = threadIdx.x;
  const float* Wg = ws + WS_W + d * 4096;
  const float* Xg = ws + WS_X + d * 4096;

#pragma unroll
  for (int j = 0; j < 4; ++j) {
    const int flat = j * 1024 + tid * 4;
    const int row = flat >> 6, col = flat & 63;
    const float4 wv = *(const float4*)&Wg[flat];
    const float4 xv = *(const float4*)&Xg[flat];
    const int o = row * BPAD + col;
#pragma unroll
    for (int s = 0; s < 2; ++s) {
      const float4 v = s ? xv : wv;
      ushort_t h0 = f2bf(v.x), h1 = f2bf(v.y), h2 = f2bf(v.z), h3 = f2bf(v.w);
      ushort_t l0 = f2bf(v.x - bfhi(v.x)), l1 = f2bf(v.y - bfhi(v.y));
      ushort_t l2 = f2bf(v.z - bfhi(v.z)), l3 = f2bf(v.w - bfhi(v.w));
      uint2 hp, lp;
      hp.x = (unsigned)h0 | ((unsigned)h1 << 16); hp.y = (unsigned)h2 | ((unsigned)h3 << 16);
      lp.x = (unsigned)l0 | ((unsigned)l1 << 16); lp.y = (unsigned)l2 | ((unsigned)l3 << 16);
      *(uint2*)&(s ? XhiL : WhiL)[o] = hp;
      *(uint2*)&(s ? XloL : WloL)[o] = lp;
    }
  }
  __syncthreads();

  const int w = tid >> 6, lane = tid & 63;
  const int lm = lane & 15, quad = lane >> 4;
  const int qrow = 16 * w + lm;
  const int koff = quad * 8;

  f32x4v acc[4];
#pragma unroll
  for (int nt = 0; nt < 4; ++nt) { acc[nt][0] = 0.f; acc[nt][1] = 0.f; acc[nt][2] = 0.f; acc[nt][3] = 0.f; }

#pragma unroll
  for (int kc = 0; kc < 64; kc += 32) {
    const bf16x8 ahi = *(const bf16x8*)&XhiL[qrow * BPAD + kc + koff];
    const bf16x8 alo = *(const bf16x8*)&XloL[qrow * BPAD + kc + koff];
#pragma unroll
    for (int nt = 0; nt < 4; ++nt) {
      const int rrow = 16 * nt + lm;
      const bf16x8 bhi = *(const bf16x8*)&WhiL[rrow * BPAD + kc + koff];
      const bf16x8 blo = *(const bf16x8*)&WloL[rrow * BPAD + kc + koff];
      acc[nt] = __builtin_amdgcn_mfma_f32_16x16x32_bf16(ahi, bhi, acc[nt], 0, 0, 0);
      acc[nt] = __builtin_amdgcn_mfma_f32_16x16x32_bf16(ahi, blo, acc[nt], 0, 0, 0);
      acc[nt] = __builtin_amdgcn_mfma_f32_16x16x32_bf16(alo, bhi, acc[nt], 0, 0, 0);
    }
  }

  if (tid == 0) acc[0][0] += Dg[d];

  float* od = out + d * 4096;
#pragma unroll
  for (int nt = 0; nt < 4; ++nt) {
#pragma unroll
    for (int reg = 0; reg < 4; ++reg) {
      const int q = 16 * w + quad * 4 + reg;
      od[q * 64 + 16 * nt + lm] = acc[nt][reg];
    }
  }
}

extern "C" void kernel_launch(void* const* d_in, const int* in_sizes, int n_in,
                              void* d_out, int out_size, void* d_ws, size_t ws_size,
                              hipStream_t stream) {
  const float* A     = (const float*)d_in[0];  // A_ct 64x64
  const float* B     = (const float*)d_in[1];  // 1024x64
  const float* C     = (const float*)d_in[2];  // 1024x64
  const float* Dv    = (const float*)d_in[3];  // 1024
  const float* logdt = (const float*)d_in[4];  // scalar
  float* ws  = (float*)d_ws;                   // 36.3 MB used
  float* out = (float*)d_out;                  // 1024*4096 fp32

  hipLaunchKernelGGL(k_setup,    dim3(1),    dim3(256), 0, stream, A, logdt, ws);
  hipLaunchKernelGGL(k_powers,   dim3(144),  dim3(256), 0, stream, B, logdt, ws);
  hipLaunchKernelGGL(k_expand,   dim3(2048), dim3(256), 0, stream, C, ws);
  hipLaunchKernelGGL(k_contract, dim3(1024), dim3(256), 0, stream, Dv, ws, out);
}